// Round 13
// baseline (978.421 us; speedup 1.0000x reference)
//
#include <hip/hip_runtime.h>

// ---------------------------------------------------------------------------
// MultiHeadQGFDLayer: out = (attn @ Wo + bo), p = diffused attention
// Round 13: epilogue write-coalescing. r12 counters: diffusion-1 WRITE_SIZE
// 275MB vs 128MB ideal (2B-scattered stores -> 32B-granule RMW); P0 combine
// reads and emit's 256MB output equally scattered. Fix: repack acc through
// the (free after K-loop) LDS with the XOR-swizzle, then do 16B-coalesced
// P0-read/combine/C-write phases. Main loops and schedule UNCHANGED from
// r12 (923us proven: r6-schedule diffusion, merged proj/stats/emit).
// ---------------------------------------------------------------------------

typedef __attribute__((ext_vector_type(8))) short bf16x8;
typedef __attribute__((ext_vector_type(4))) short s16x4;
typedef __attribute__((ext_vector_type(4))) float f32x4;

constexpr int N_TOK   = 2048;
constexpr int N_HEADS = 16;
constexpr int HD      = 64;
constexpr int EMB     = 1024;

#define DEVINL __device__ __forceinline__

DEVINL unsigned short f2bf_u(float f) {           // f32 -> bf16 (RTNE)
  unsigned x = __float_as_uint(f);
  return (unsigned short)((x + 0x7fffu + ((x >> 16) & 1u)) >> 16);
}
DEVINL float bf2f_u(unsigned short h) { return __uint_as_float(((unsigned)h) << 16); }

DEVINL void async16(const void* src, void* dst) { // global -> LDS, 16B/lane
  __builtin_amdgcn_global_load_lds(
      (const __attribute__((address_space(1))) void*)src,
      (__attribute__((address_space(3))) void*)dst, 16, 0, 0);
}

enum : int { EPI_F32SCALE = 0, EPI_F32BIAS, EPI_BF16, EPI_QKSPLIT, EPI_VSPLIT,
             EPI_DIFF_BF16, EPI_DIFF_F32 };

// ===========================================================================
// Merged QK^T / KK^T row stats: grid (16 rowblocks, 32).
// y<16: A=Q[head] -> mxq/isq ; y>=16: A=K[head] -> mxk/isk. B=K[head] always.
// ===========================================================================
__global__ __launch_bounds__(256)
void gemm_stats(const unsigned short* __restrict__ Qm,
                const unsigned short* __restrict__ Km, long long sH_,
                float* __restrict__ mxq, float* __restrict__ isq,
                float* __restrict__ mxk, float* __restrict__ isk)
{
  __shared__ __align__(16) char smem[3 * 16384];      // A 16KB + B dbuf 2x16KB
  __shared__ float lred[2][2][128];                   // [max|sum][wc][row]
  const int tid = threadIdx.x, lane = tid & 63, wv = tid >> 6;
  const int wr = wv >> 1, wc = wv & 1, l15 = lane & 15, g = lane >> 4;
  const int y = blockIdx.y;
  const size_t head = (size_t)(y & 15);
  const int sel = y >> 4;
  const unsigned short* Az = (sel ? Km : Qm) + head * (size_t)sH_
                             + (size_t)blockIdx.x * 128 * HD;
  const unsigned short* Bz = Km + head * (size_t)sH_;
  float* mxo = sel ? mxk : mxq;
  float* iso = sel ? isk : isq;
  const float alpha = 0.125f;
  const int cbs = (tid & 7) * 16;
  const int rr = tid >> 3;                            // 0..31

  #pragma unroll
  for (int i = 0; i < 4; ++i) {                       // A rows of this block
    const int r = i * 32 + rr;
    async16((const char*)Az + (size_t)r * 128 + (cbs ^ ((r & 7) << 4)),
            smem + i * 4096 + wv * 1024);
  }
  #pragma unroll
  for (int i = 0; i < 4; ++i) {                       // B tile 0 -> buf0
    const int r = i * 32 + rr;
    async16((const char*)Bz + (size_t)r * 128 + (cbs ^ ((r & 7) << 4)),
            smem + 16384 + i * 4096 + wv * 1024);
  }
  __syncthreads();

  float rm[4][4], rs[4][4];
  #pragma unroll
  for (int m = 0; m < 4; ++m)
    #pragma unroll
    for (int j = 0; j < 4; ++j) { rm[m][j] = -3.0e38f; rs[m][j] = 0.f; }

  for (int ct = 0; ct < 16; ++ct) {
    const int cur = ct & 1;
    if (ct + 1 < 16) {
      const int nb = cur ^ 1;
      #pragma unroll
      for (int i = 0; i < 4; ++i) {
        const int r = i * 32 + rr;
        const size_t br = (size_t)(ct + 1) * 128 + r;
        async16((const char*)Bz + br * 128 + (cbs ^ ((r & 7) << 4)),
                smem + 16384 + nb * 16384 + i * 4096 + wv * 1024);
      }
    }
    f32x4 acc[4][4];
    #pragma unroll
    for (int m = 0; m < 4; ++m)
      #pragma unroll
      for (int n = 0; n < 4; ++n) acc[m][n] = f32x4{0.f, 0.f, 0.f, 0.f};
    #pragma unroll
    for (int kk = 0; kk < 2; ++kk) {
      bf16x8 a[4], b[4];
      #pragma unroll
      for (int m = 0; m < 4; ++m) {
        const int row = wr * 64 + m * 16 + l15;
        const int c = (kk * 64 + g * 16) ^ ((row & 7) << 4);
        a[m] = *(const bf16x8*)(smem + row * 128 + c);
      }
      #pragma unroll
      for (int n = 0; n < 4; ++n) {
        const int row = wc * 64 + n * 16 + l15;
        const int c = (kk * 64 + g * 16) ^ ((row & 7) << 4);
        b[n] = *(const bf16x8*)(smem + 16384 + cur * 16384 + row * 128 + c);
      }
      #pragma unroll
      for (int m = 0; m < 4; ++m)
        #pragma unroll
        for (int n = 0; n < 4; ++n)
          acc[m][n] = __builtin_amdgcn_mfma_f32_16x16x32_bf16(a[m], b[n], acc[m][n], 0, 0, 0);
    }
    #pragma unroll
    for (int m = 0; m < 4; ++m)
    #pragma unroll
    for (int j = 0; j < 4; ++j) {
      const float v0 = acc[m][0][j] * alpha, v1 = acc[m][1][j] * alpha;
      const float v2 = acc[m][2][j] * alpha, v3 = acc[m][3][j] * alpha;
      const float pm = fmaxf(fmaxf(v0, v1), fmaxf(v2, v3));
      const float nm = fmaxf(rm[m][j], pm);
      rs[m][j] = rs[m][j] * expf(rm[m][j] - nm)
               + expf(v0 - nm) + expf(v1 - nm) + expf(v2 - nm) + expf(v3 - nm);
      rm[m][j] = nm;
    }
    __syncthreads();
  }

  #pragma unroll
  for (int off = 1; off < 16; off <<= 1) {
    #pragma unroll
    for (int m = 0; m < 4; ++m)
    #pragma unroll
    for (int j = 0; j < 4; ++j) {
      const float om = __shfl_xor(rm[m][j], off);
      const float os = __shfl_xor(rs[m][j], off);
      const float nm = fmaxf(rm[m][j], om);
      rs[m][j] = rs[m][j] * expf(rm[m][j] - nm) + os * expf(om - nm);
      rm[m][j] = nm;
    }
  }
  if (l15 == 0) {
    #pragma unroll
    for (int m = 0; m < 4; ++m)
    #pragma unroll
    for (int j = 0; j < 4; ++j) {
      const int r = wr * 64 + m * 16 + g * 4 + j;
      lred[0][wc][r] = rm[m][j];
      lred[1][wc][r] = rs[m][j];
    }
  }
  __syncthreads();
  if (tid < 128) {
    const float m0 = lred[0][0][tid], m1 = lred[0][1][tid];
    const float M = fmaxf(m0, m1);
    const float S = lred[1][0][tid] * expf(m0 - M) + lred[1][1][tid] * expf(m1 - M);
    mxo[head * N_TOK + (size_t)blockIdx.x * 128 + tid] = M;
    iso[head * N_TOK + (size_t)blockIdx.x * 128 + tid] = 1.0f / S;
  }
}

// ===========================================================================
// Merged emit: grid (16,16,32). z<16: p0 = rownorm exp(QK^T/8) -> p0b[head];
// z>=16: PT = colnorm exp(KK^T/8) -> PT[head] (sim symmetry). K=64.
// Epilogue: normalize into swizzled LDS, then coalesced 16B stores.
// ===========================================================================
__global__ __launch_bounds__(256)
void emit_merged(const unsigned short* __restrict__ Qm,
                 const unsigned short* __restrict__ Km, long long sH_,
                 const float* __restrict__ mxq, const float* __restrict__ isq,
                 const float* __restrict__ mxk, const float* __restrict__ isk,
                 unsigned short* __restrict__ p0b, unsigned short* __restrict__ PTb,
                 long long sNN)
{
  constexpr int BKk = 64;
  __shared__ __align__(16) char smem[128 * BKk * 2 + 128 * BKk * 2];  // 32 KB
  const int tid  = threadIdx.x;
  const int lane = tid & 63, wv = tid >> 6;
  const int wr = wv >> 1, wc = wv & 1;
  const int l15 = lane & 15, g = lane >> 4;
  const int zz = blockIdx.z;
  const size_t head = (size_t)(zz & 15);
  const int col = zz >> 4;
  const size_t brow = (size_t)blockIdx.y * 128;
  const size_t bcol = (size_t)blockIdx.x * 128;

  const unsigned short* Ab = (col ? Km : Qm) + head * (size_t)sH_;
  const unsigned short* Bb = Km + head * (size_t)sH_;
  unsigned short* Cu = (col ? PTb : p0b) + head * (size_t)sNN;
  const float* mxp = col ? mxk : mxq;
  const float* isp = col ? isk : isq;

  f32x4 acc[4][4];
  #pragma unroll
  for (int m = 0; m < 4; ++m)
    #pragma unroll
    for (int n = 0; n < 4; ++n) acc[m][n] = f32x4{0.f, 0.f, 0.f, 0.f};

  { // single K-tile (K = 64): 128 rows x 8 chunks = 1024 chunks = 4 iters
    #pragma unroll
    for (int i = 0; i < 4; ++i) {
      const int c   = i * 256 + wv * 64 + lane;
      const int row = c / 8;
      const int eo  = (c % 8) * 8;
      async16(Ab + (brow + row) * (size_t)HD + eo,
              smem + (size_t)(i * 256 + wv * 64) * 16);
    }
    #pragma unroll
    for (int i = 0; i < 4; ++i) {
      const int c   = i * 256 + wv * 64 + lane;
      const int row = c / 8;
      const int eo  = (c % 8) * 8;
      async16(Bb + (bcol + row) * (size_t)HD + eo,
              smem + 16384 + (size_t)(i * 256 + wv * 64) * 16);
    }
    __syncthreads();
    #pragma unroll
    for (int kk = 0; kk < 2; ++kk) {
      bf16x8 a[4], b[4];
      #pragma unroll
      for (int m = 0; m < 4; ++m) {
        const int r = wr * 64 + m * 16 + l15;
        a[m] = *(const bf16x8*)(smem + ((size_t)r * BKk + kk * 32 + g * 8) * 2);
      }
      #pragma unroll
      for (int n = 0; n < 4; ++n) {
        const int cc = wc * 64 + n * 16 + l15;
        b[n] = *(const bf16x8*)(smem + 16384 + ((size_t)cc * BKk + kk * 32 + g * 8) * 2);
      }
      #pragma unroll
      for (int m = 0; m < 4; ++m)
        #pragma unroll
        for (int n = 0; n < 4; ++n)
          acc[m][n] = __builtin_amdgcn_mfma_f32_16x16x32_bf16(a[m], b[n], acc[m][n], 0, 0, 0);
    }
    __syncthreads();   // LDS reads done -> safe to reuse smem for repack
  }

  // ---- repack: normalize into swizzled LDS (128 rows x 256B), coalesced out
  #pragma unroll
  for (int m = 0; m < 4; ++m)
  #pragma unroll
  for (int n = 0; n < 4; ++n)
  #pragma unroll
  for (int j = 0; j < 4; ++j) {
    const int row = wr * 64 + m * 16 + g * 4 + j;          // 0..127
    const int cb  = (wc * 64 + n * 16 + l15) * 2;          // byte col 0..254
    const size_t R  = brow + row;
    const size_t Cc = bcol + (size_t)(cb >> 1);
    const size_t si = head * N_TOK + (col ? Cc : R);
    const float v = acc[m][n][j] * 0.125f;
    *(unsigned short*)(smem + row * 256 + (cb ^ ((row & 7) << 4))) =
        f2bf_u(expf(v - mxp[si]) * isp[si]);
  }
  __syncthreads();
  #pragma unroll
  for (int i = 0; i < 8; ++i) {                            // 2048 chunks of 16B
    const int chunk = i * 256 + tid;
    const int row = chunk >> 4, s = chunk & 15;
    const bf16x8 v = *(const bf16x8*)(smem + row * 256 + ((s * 16) ^ ((row & 7) << 4)));
    *(bf16x8*)(Cu + (brow + row) * (size_t)N_TOK + bcol + s * 8) = v;
  }
}

// ===========================================================================
// Merged QKV projection: grid (8,16,3). z selects W/bias/epilogue.
// z<2: head-split [h][n][d] (Q or K); z=2: transposed split [h][d][n] (V).
// ===========================================================================
__global__ __launch_bounds__(256)
void proj_qkv(const unsigned short* __restrict__ Xbf,
              const unsigned short* __restrict__ W0, const unsigned short* __restrict__ W1,
              const unsigned short* __restrict__ W2,
              const float* __restrict__ b0, const float* __restrict__ b1,
              const float* __restrict__ b2,
              unsigned short* __restrict__ Qb, unsigned short* __restrict__ Kb,
              unsigned short* __restrict__ Vt)
{
  constexpr int BKk = 64;
  __shared__ __align__(16) char smem[2 * 128 * BKk * 2];
  const int tid  = threadIdx.x;
  const int lane = tid & 63, wv = tid >> 6;
  const int wr = wv >> 1, wc = wv & 1;
  const int l15 = lane & 15, g = lane >> 4;
  const int z = blockIdx.z;
  const size_t brow = (size_t)blockIdx.y * 128;
  const size_t bcol = (size_t)blockIdx.x * 128;

  const unsigned short* Bb = z == 0 ? W0 : (z == 1 ? W1 : W2);
  const float* bias = z == 0 ? b0 : (z == 1 ? b1 : b2);

  f32x4 acc[4][4];
  #pragma unroll
  for (int m = 0; m < 4; ++m)
    #pragma unroll
    for (int n = 0; n < 4; ++n) acc[m][n] = f32x4{0.f, 0.f, 0.f, 0.f};

  for (int k0 = 0; k0 < EMB; k0 += BKk) {
    #pragma unroll
    for (int i = 0; i < 4; ++i) {   // 128 rows x 8 chunks = 4 iters
      const int c   = i * 256 + wv * 64 + lane;
      const int row = c / 8;
      const int eo  = (c % 8) * 8;
      async16(Xbf + (brow + row) * (size_t)EMB + (size_t)(k0 + eo),
              smem + (size_t)(i * 256 + wv * 64) * 16);
    }
    #pragma unroll
    for (int i = 0; i < 4; ++i) {
      const int c   = i * 256 + wv * 64 + lane;
      const int row = c / 8;
      const int eo  = (c % 8) * 8;
      async16(Bb + (bcol + row) * (size_t)EMB + (size_t)(k0 + eo),
              smem + 16384 + (size_t)(i * 256 + wv * 64) * 16);
    }
    __syncthreads();
    #pragma unroll
    for (int kk = 0; kk < 2; ++kk) {
      bf16x8 a[4], b[4];
      #pragma unroll
      for (int m = 0; m < 4; ++m) {
        const int r = wr * 64 + m * 16 + l15;
        a[m] = *(const bf16x8*)(smem + ((size_t)r * BKk + kk * 32 + g * 8) * 2);
      }
      #pragma unroll
      for (int n = 0; n < 4; ++n) {
        const int cc = wc * 64 + n * 16 + l15;
        b[n] = *(const bf16x8*)(smem + 16384 + ((size_t)cc * BKk + kk * 32 + g * 8) * 2);
      }
      #pragma unroll
      for (int m = 0; m < 4; ++m)
        #pragma unroll
        for (int n = 0; n < 4; ++n)
          acc[m][n] = __builtin_amdgcn_mfma_f32_16x16x32_bf16(a[m], b[n], acc[m][n], 0, 0, 0);
    }
    __syncthreads();
  }

  unsigned short* dstQK = z ? Kb : Qb;
  #pragma unroll
  for (int m = 0; m < 4; ++m)
  #pragma unroll
  for (int n = 0; n < 4; ++n)
  #pragma unroll
  for (int j = 0; j < 4; ++j) {
    const size_t R  = brow + (size_t)(wr * 64 + m * 16 + g * 4 + j);
    const size_t Cc = bcol + (size_t)(wc * 64 + n * 16 + l15);
    const float t = acc[m][n][j] + bias[Cc];
    if (z == 2)
      Vt[(Cc >> 6) * ((size_t)HD * N_TOK) + (Cc & 63) * (size_t)N_TOK + R] = f2bf_u(t);
    else
      dstQK[(Cc >> 6) * ((size_t)N_TOK * HD) + R * HD + (Cc & 63)] = f2bf_u(t);
  }
}

// ===========================================================================
// 256x256 pipelined diffusion GEMM (r6 schedule, main loop verbatim).
// Epilogue: repack acc via swizzled LDS; coalesced P0-read/combine/C-write.
// ===========================================================================
template<int EPI>
__global__ __launch_bounds__(512, 2)
void gemm256_diff(const unsigned short* __restrict__ Am, int lda, long long sAz,
                  const unsigned short* __restrict__ Bm, int ldb, long long sBz,
                  int K,
                  const unsigned short* __restrict__ P0, int ldp0, long long sPz,
                  void* __restrict__ Cv, int ldc, long long sCz)
{
  __shared__ __align__(16) char smem[2 * 65536];  // 128 KiB
  const int tid  = threadIdx.x;
  const int lane = tid & 63, wv = tid >> 6;
  const int wr = wv >> 2, wc = wv & 3;            // 2 x 4 wave grid
  const int l15 = lane & 15, g = lane >> 4;
  const int z = blockIdx.z;
  const size_t brow = (size_t)blockIdx.y * 256;
  const size_t bcol = (size_t)blockIdx.x * 256;

  const unsigned short* Ab = Am + (size_t)z * (size_t)sAz;
  const unsigned short* Bb = Bm + (size_t)z * (size_t)sBz;
  const int NT = K >> 6;

  const int cbs = (tid & 7) * 16;
  const int r00 = (tid >> 3),       r01 = 64  + (tid >> 3);
  const int r10 = 128 + (tid >> 3), r11 = 192 + (tid >> 3);
  const char* gA00 = (const char*)Ab + ((brow + r00) * (size_t)lda) * 2 + (cbs ^ ((r00 & 7) << 4));
  const char* gA01 = (const char*)Ab + ((brow + r01) * (size_t)lda) * 2 + (cbs ^ ((r01 & 7) << 4));
  const char* gA10 = (const char*)Ab + ((brow + r10) * (size_t)lda) * 2 + (cbs ^ ((r10 & 7) << 4));
  const char* gA11 = (const char*)Ab + ((brow + r11) * (size_t)lda) * 2 + (cbs ^ ((r11 & 7) << 4));
  const char* gB00 = (const char*)Bb + ((bcol + r00) * (size_t)ldb) * 2 + (cbs ^ ((r00 & 7) << 4));
  const char* gB01 = (const char*)Bb + ((bcol + r01) * (size_t)ldb) * 2 + (cbs ^ ((r01 & 7) << 4));
  const char* gB10 = (const char*)Bb + ((bcol + r10) * (size_t)ldb) * 2 + (cbs ^ ((r10 & 7) << 4));
  const char* gB11 = (const char*)Bb + ((bcol + r11) * (size_t)ldb) * 2 + (cbs ^ ((r11 & 7) << 4));

  f32x4 acc[8][4];
  #pragma unroll
  for (int m = 0; m < 8; ++m)
    #pragma unroll
    for (int n = 0; n < 4; ++n) acc[m][n] = f32x4{0.f, 0.f, 0.f, 0.f};

  auto ldA = [&](int cur, int mf, int kk) -> bf16x8 {
    const int row = wr * 128 + mf * 16 + l15;
    const int c = (kk * 64 + g * 16) ^ ((row & 7) << 4);
    return *(const bf16x8*)(smem + cur * 65536 + row * 128 + c);
  };
  auto ldB = [&](int cur, int nf, int kk) -> bf16x8 {
    const int row = wc * 64 + nf * 16 + l15;
    const int c = (kk * 64 + g * 16) ^ ((row & 7) << 4);
    return *(const bf16x8*)(smem + cur * 65536 + 32768 + row * 128 + c);
  };

  {
    char* d0 = smem;
    async16(gA00, d0 +             wv * 1024);
    async16(gA01, d0 +  8192 +     wv * 1024);
    async16(gA10, d0 + 16384 +     wv * 1024);
    async16(gA11, d0 + 24576 +     wv * 1024);
    async16(gB00, d0 + 32768 +     wv * 1024);
    async16(gB01, d0 + 40960 +     wv * 1024);
    async16(gB10, d0 + 49152 +     wv * 1024);
    async16(gB11, d0 + 57344 +     wv * 1024);
    if (NT > 1) {
      char* d1 = smem + 65536 + 32768;
      async16(gB00 + 128, d1 +             wv * 1024);
      async16(gB01 + 128, d1 +  8192 +     wv * 1024);
      async16(gB10 + 128, d1 + 16384 +     wv * 1024);
      async16(gB11 + 128, d1 + 24576 +     wv * 1024);
      asm volatile("s_waitcnt vmcnt(4)" ::: "memory");
    } else {
      asm volatile("s_waitcnt vmcnt(0)" ::: "memory");
    }
    __builtin_amdgcn_sched_barrier(0);
    __builtin_amdgcn_s_barrier();
  }

#define READA(P, Q)                                                       \
    bf16x8 P##00 = ldA(cur, 2*(Q),   0), P##01 = ldA(cur, 2*(Q),   1),    \
           P##10 = ldA(cur, 2*(Q)+1, 0), P##11 = ldA(cur, 2*(Q)+1, 1);

#define MFMA16(P, Q)                                                                        \
    __builtin_amdgcn_s_setprio(1);                                                          \
    acc[2*(Q)+0][0] = __builtin_amdgcn_mfma_f32_16x16x32_bf16(P##00, b00, acc[2*(Q)+0][0], 0, 0, 0); \
    acc[2*(Q)+0][1] = __builtin_amdgcn_mfma_f32_16x16x32_bf16(P##00, b10, acc[2*(Q)+0][1], 0, 0, 0); \
    acc[2*(Q)+0][2] = __builtin_amdgcn_mfma_f32_16x16x32_bf16(P##00, b20, acc[2*(Q)+0][2], 0, 0, 0); \
    acc[2*(Q)+0][3] = __builtin_amdgcn_mfma_f32_16x16x32_bf16(P##00, b30, acc[2*(Q)+0][3], 0, 0, 0); \
    acc[2*(Q)+1][0] = __builtin_amdgcn_mfma_f32_16x16x32_bf16(P##10, b00, acc[2*(Q)+1][0], 0, 0, 0); \
    acc[2*(Q)+1][1] = __builtin_amdgcn_mfma_f32_16x16x32_bf16(P##10, b10, acc[2*(Q)+1][1], 0, 0, 0); \
    acc[2*(Q)+1][2] = __builtin_amdgcn_mfma_f32_16x16x32_bf16(P##10, b20, acc[2*(Q)+1][2], 0, 0, 0); \
    acc[2*(Q)+1][3] = __builtin_amdgcn_mfma_f32_16x16x32_bf16(P##10, b30, acc[2*(Q)+1][3], 0, 0, 0); \
    acc[2*(Q)+0][0] = __builtin_amdgcn_mfma_f32_16x16x32_bf16(P##01, b01, acc[2*(Q)+0][0], 0, 0, 0); \
    acc[2*(Q)+0][1] = __builtin_amdgcn_mfma_f32_16x16x32_bf16(P##01, b11, acc[2*(Q)+0][1], 0, 0, 0); \
    acc[2*(Q)+0][2] = __builtin_amdgcn_mfma_f32_16x16x32_bf16(P##01, b21, acc[2*(Q)+0][2], 0, 0, 0); \
    acc[2*(Q)+0][3] = __builtin_amdgcn_mfma_f32_16x16x32_bf16(P##01, b31, acc[2*(Q)+0][3], 0, 0, 0); \
    acc[2*(Q)+1][0] = __builtin_amdgcn_mfma_f32_16x16x32_bf16(P##11, b01, acc[2*(Q)+1][0], 0, 0, 0); \
    acc[2*(Q)+1][1] = __builtin_amdgcn_mfma_f32_16x16x32_bf16(P##11, b11, acc[2*(Q)+1][1], 0, 0, 0); \
    acc[2*(Q)+1][2] = __builtin_amdgcn_mfma_f32_16x16x32_bf16(P##11, b21, acc[2*(Q)+1][2], 0, 0, 0); \
    acc[2*(Q)+1][3] = __builtin_amdgcn_mfma_f32_16x16x32_bf16(P##11, b31, acc[2*(Q)+1][3], 0, 0, 0); \
    __builtin_amdgcn_s_setprio(0);

#define SB __builtin_amdgcn_sched_barrier(0)

  int cur = 0;
  for (int t = 0; t < NT; ++t, cur ^= 1) {
    const int o = cur ^ 1;
    const size_t ko1 = (size_t)(t + 1) * 128;
    const size_t ko2 = (size_t)(t + 2) * 128;
    bf16x8 b00 = ldB(cur, 0, 0), b01 = ldB(cur, 0, 1);
    bf16x8 b10 = ldB(cur, 1, 0), b11 = ldB(cur, 1, 1);
    bf16x8 b20 = ldB(cur, 2, 0), b21 = ldB(cur, 2, 1);
    bf16x8 b30 = ldB(cur, 3, 0), b31 = ldB(cur, 3, 1);
    READA(f0_, 0)
    READA(f1_, 1)
    if (t + 1 < NT) {
      char* d = smem + o * 65536;
      async16(gA00 + ko1, d +        wv * 1024);
      async16(gA01 + ko1, d + 8192 + wv * 1024);
    }
    asm volatile("s_waitcnt lgkmcnt(4)" ::: "memory");
    SB;
    MFMA16(f0_, 0)
    READA(f2_, 2)
    if (t + 1 < NT) {
      char* d = smem + o * 65536;
      async16(gA10 + ko1, d + 16384 + wv * 1024);
      async16(gA11 + ko1, d + 24576 + wv * 1024);
    }
    asm volatile("s_waitcnt lgkmcnt(4)" ::: "memory");
    SB;
    MFMA16(f1_, 1)
    SB;
    __builtin_amdgcn_s_barrier();   // all waves hold B(t) in regs now
    READA(f3_, 3)
    if (t + 2 < NT) {
      char* d = smem + cur * 65536 + 32768;
      async16(gB00 + ko2, d +        wv * 1024);
      async16(gB01 + ko2, d + 8192 + wv * 1024);
    }
    asm volatile("s_waitcnt lgkmcnt(4)" ::: "memory");
    SB;
    MFMA16(f2_, 2)
    if (t + 2 < NT) {
      char* d = smem + cur * 65536 + 32768 + 16384;
      async16(gB10 + ko2, d +        wv * 1024);
      async16(gB11 + ko2, d + 8192 + wv * 1024);
    }
    asm volatile("s_waitcnt lgkmcnt(0)" ::: "memory");
    SB;
    MFMA16(f3_, 3)
    if (t + 1 < NT) {
      if (t + 2 < NT) asm volatile("s_waitcnt vmcnt(4)" ::: "memory");
      else            asm volatile("s_waitcnt vmcnt(0)" ::: "memory");
      SB;
      __builtin_amdgcn_s_barrier();
    }
  }
#undef MFMA16
#undef READA
#undef SB

  // ---- epilogue: repack acc -> swizzled LDS (256 rows x 512B = 128KB),
  // then coalesced 16B P0-read + combine + 16B C-write.
  __syncthreads();                       // all K-loop LDS reads complete
  #pragma unroll
  for (int m = 0; m < 8; ++m)
  #pragma unroll
  for (int n = 0; n < 4; ++n)
  #pragma unroll
  for (int j = 0; j < 4; ++j) {
    const int row = wr * 128 + m * 16 + g * 4 + j;      // 0..255
    const int cb  = (wc * 64 + n * 16 + l15) * 2;       // byte col 0..510
    *(unsigned short*)(smem + row * 512 + (cb ^ ((row & 7) << 4))) =
        f2bf_u(acc[m][n][j]);
  }
  __syncthreads();
  float* Cf = (float*)Cv + (size_t)z * (size_t)sCz;
  unsigned short* Cu = (unsigned short*)Cv + (size_t)z * (size_t)sCz;
  const unsigned short* P0z = P0 + (size_t)z * (size_t)sPz;
  #pragma unroll
  for (int i = 0; i < 16; ++i) {                        // 8192 chunks of 16B
    const int chunk = i * 512 + tid;
    const int row = chunk >> 5, s = chunk & 31;
    const bf16x8 av = *(const bf16x8*)(smem + row * 512 + ((s * 16) ^ ((row & 7) << 4)));
    const bf16x8 pv = *(const bf16x8*)(P0z + (brow + row) * (size_t)ldp0 + bcol + s * 8);
    if constexpr (EPI == EPI_DIFF_BF16) {
      bf16x8 ov;
      #pragma unroll
      for (int k = 0; k < 8; ++k)
        ov[k] = (short)f2bf_u(0.7f * bf2f_u((unsigned short)pv[k])
                            + 0.3f * bf2f_u((unsigned short)av[k]));
      *(bf16x8*)(Cu + (brow + row) * (size_t)ldc + bcol + s * 8) = ov;
    } else {
      f32x4 lo, hi;
      #pragma unroll
      for (int k = 0; k < 4; ++k) {
        lo[k] = 0.7f * bf2f_u((unsigned short)pv[k])
              + 0.3f * bf2f_u((unsigned short)av[k]);
        hi[k] = 0.7f * bf2f_u((unsigned short)pv[4 + k])
              + 0.3f * bf2f_u((unsigned short)av[4 + k]);
      }
      float* dst = Cf + (brow + row) * (size_t)ldc + bcol + s * 8;
      *(f32x4*)dst = lo;
      *(f32x4*)(dst + 4) = hi;
    }
  }
}

// ===========================================================================
// 128-tile kernel (pV, Wo, fallback path).
// ===========================================================================
template<int BM, int BN, bool AF32, int EPI>
__global__ __launch_bounds__(256)
void gemm_tn(const void* __restrict__ Av, int lda, long long sAz,
             const unsigned short* __restrict__ Bm, int ldb, long long sBz,
             int K, float alpha, const float* __restrict__ bias,
             const unsigned short* __restrict__ P0, int ldp0, long long sPz,
             void* __restrict__ Cv, int ldc, long long sCz)
{
  constexpr int BKk = 64;
  constexpr int WM = BM / 2, WN = BN / 2, MF = WM / 16, NF = WN / 16;
  constexpr int AES = AF32 ? 4 : 2;
  constexpr int ABYTES = BM * BKk * AES, BBYTES = BN * BKk * 2;
  __shared__ __align__(16) char smem[ABYTES + BBYTES];

  const int tid  = threadIdx.x;
  const int lane = tid & 63, wv = tid >> 6;
  const int wr = wv >> 1, wc = wv & 1;
  const int l15 = lane & 15, g = lane >> 4;
  const int z = blockIdx.z;
  const size_t brow = (size_t)blockIdx.y * BM;
  const size_t bcol = (size_t)blockIdx.x * BN;

  const char* Ab = (const char*)Av + (size_t)z * (size_t)sAz * AES;
  const unsigned short* Bb = Bm + (size_t)z * (size_t)sBz;

  f32x4 acc[MF][NF];
  #pragma unroll
  for (int m = 0; m < MF; ++m)
    #pragma unroll
    for (int n = 0; n < NF; ++n)
      acc[m][n] = f32x4{0.f, 0.f, 0.f, 0.f};

  constexpr int EPC_A = AF32 ? 4 : 8;
  constexpr int CPR_A = BKk / EPC_A;
  constexpr int IT_A  = (BM * CPR_A) / 256;
  constexpr int CPR_B = 8;
  constexpr int IT_B  = (BN * CPR_B) / 256;

  for (int k0 = 0; k0 < K; k0 += BKk) {
    #pragma unroll
    for (int i = 0; i < IT_A; ++i) {
      const int c   = i * 256 + wv * 64 + lane;
      const int row = c / CPR_A;
      const int eo  = (c % CPR_A) * EPC_A;
      const char* src = Ab + ((brow + row) * (size_t)lda + (size_t)(k0 + eo)) * AES;
      async16(src, smem + (size_t)(i * 256 + wv * 64) * 16);
    }
    #pragma unroll
    for (int i = 0; i < IT_B; ++i) {
      const int c   = i * 256 + wv * 64 + lane;
      const int row = c / CPR_B;
      const int eo  = (c % CPR_B) * 8;
      const unsigned short* src = Bb + (bcol + row) * (size_t)ldb + (size_t)(k0 + eo);
      async16(src, smem + ABYTES + (size_t)(i * 256 + wv * 64) * 16);
    }
    __syncthreads();
    #pragma unroll
    for (int kk = 0; kk < 2; ++kk) {
      bf16x8 a[MF], b[NF];
      #pragma unroll
      for (int m = 0; m < MF; ++m) {
        const int r = wr * WM + m * 16 + l15;
        if constexpr (!AF32) {
          a[m] = *(const bf16x8*)(smem + ((size_t)r * BKk + kk * 32 + g * 8) * 2);
        } else {
          const float* pa = (const float*)smem + (size_t)r * BKk + kk * 32 + g * 8;
          const f32x4 lo = *(const f32x4*)pa;
          const f32x4 hi = *(const f32x4*)(pa + 4);
          bf16x8 t;
          t[0] = (short)f2bf_u(lo[0]); t[1] = (short)f2bf_u(lo[1]);
          t[2] = (short)f2bf_u(lo[2]); t[3] = (short)f2bf_u(lo[3]);
          t[4] = (short)f2bf_u(hi[0]); t[5] = (short)f2bf_u(hi[1]);
          t[6] = (short)f2bf_u(hi[2]); t[7] = (short)f2bf_u(hi[3]);
          a[m] = t;
        }
      }
      #pragma unroll
      for (int n = 0; n < NF; ++n) {
        const int cc = wc * WN + n * 16 + l15;
        b[n] = *(const bf16x8*)(smem + ABYTES + ((size_t)cc * BKk + kk * 32 + g * 8) * 2);
      }
      #pragma unroll
      for (int m = 0; m < MF; ++m)
        #pragma unroll
        for (int n = 0; n < NF; ++n)
          acc[m][n] = __builtin_amdgcn_mfma_f32_16x16x32_bf16(a[m], b[n], acc[m][n], 0, 0, 0);
    }
    __syncthreads();
  }

  float* Cf = (float*)Cv + (size_t)z * (size_t)sCz;
  unsigned short* Cu = (unsigned short*)Cv + (size_t)z * (size_t)sCz;

  #pragma unroll
  for (int m = 0; m < MF; ++m)
  #pragma unroll
  for (int n = 0; n < NF; ++n)
  #pragma unroll
  for (int j = 0; j < 4; ++j) {
    const size_t R  = brow + (size_t)(wr * WM + m * 16 + g * 4 + j);
    const size_t Cc = bcol + (size_t)(wc * WN + n * 16 + l15);
    const float v = acc[m][n][j];
    if constexpr (EPI == EPI_F32SCALE) {
      Cf[R * ldc + Cc] = v * alpha;
    } else if constexpr (EPI == EPI_F32BIAS) {
      Cf[R * ldc + Cc] = v + bias[Cc];
    } else if constexpr (EPI == EPI_BF16) {
      Cu[R * ldc + Cc] = f2bf_u(v);
    } else if constexpr (EPI == EPI_DIFF_BF16) {
      const unsigned short* P0z = P0 + (size_t)z * (size_t)sPz;
      const float p0v = bf2f_u(P0z[R * (size_t)ldp0 + Cc]);
      Cu[R * ldc + Cc] = f2bf_u(0.7f * p0v + 0.3f * v);
    } else if constexpr (EPI == EPI_DIFF_F32) {
      const unsigned short* P0z = P0 + (size_t)z * (size_t)sPz;
      const float p0v = bf2f_u(P0z[R * (size_t)ldp0 + Cc]);
      Cf[R * ldc + Cc] = 0.7f * p0v + 0.3f * v;
    }
  }
  (void)alpha; (void)bias; (void)P0; (void)ldp0;
}

// Row softmax (fallback path only)
__global__ __launch_bounds__(256)
void row_softmax(const float* __restrict__ S, long long sS,
                 unsigned short* __restrict__ O, long long sO)
{
  __shared__ float red[8];
  const int tid = threadIdx.x;
  const size_t row = blockIdx.x;
  const size_t h = blockIdx.y;
  const f32x4* Sr = (const f32x4*)(S + (size_t)h * sS + row * N_TOK);
  f32x4 v0 = Sr[tid], v1 = Sr[tid + 256];
  float m = fmaxf(fmaxf(fmaxf(v0[0], v0[1]), fmaxf(v0[2], v0[3])),
                  fmaxf(fmaxf(v1[0], v1[1]), fmaxf(v1[2], v1[3])));
  #pragma unroll
  for (int o = 32; o; o >>= 1) m = fmaxf(m, __shfl_xor(m, o));
  if ((tid & 63) == 0) red[tid >> 6] = m;
  __syncthreads();
  m = fmaxf(fmaxf(red[0], red[1]), fmaxf(red[2], red[3]));
  f32x4 e0, e1;
  #pragma unroll
  for (int k = 0; k < 4; ++k) { e0[k] = expf(v0[k] - m); e1[k] = expf(v1[k] - m); }
  float s = e0[0]+e0[1]+e0[2]+e0[3]+e1[0]+e1[1]+e1[2]+e1[3];
  #pragma unroll
  for (int o = 32; o; o >>= 1) s += __shfl_xor(s, o);
  if ((tid & 63) == 0) red[4 + (tid >> 6)] = s;
  __syncthreads();
  s = red[4] + red[5] + red[6] + red[7];
  const float inv = 1.0f / s;
  s16x4 o0, o1;
  #pragma unroll
  for (int k = 0; k < 4; ++k) {
    o0[k] = (short)f2bf_u(e0[k] * inv);
    o1[k] = (short)f2bf_u(e1[k] * inv);
  }
  s16x4* Or = (s16x4*)(O + (size_t)h * sO + row * N_TOK);
  Or[tid] = o0; Or[tid + 256] = o1;
}

// Row stats (fallback path only)
__global__ __launch_bounds__(256)
void row_reduce(const float* __restrict__ S, long long sS,
                float* __restrict__ mx, float* __restrict__ is_)
{
  __shared__ float red[8];
  const int tid = threadIdx.x;
  const size_t row = blockIdx.x;
  const size_t h = blockIdx.y;
  const f32x4* Sr = (const f32x4*)(S + (size_t)h * sS + row * N_TOK);
  f32x4 v0 = Sr[tid], v1 = Sr[tid + 256];
  float m = fmaxf(fmaxf(fmaxf(v0[0], v0[1]), fmaxf(v0[2], v0[3])),
                  fmaxf(fmaxf(v1[0], v1[1]), fmaxf(v1[2], v1[3])));
  #pragma unroll
  for (int o = 32; o; o >>= 1) m = fmaxf(m, __shfl_xor(m, o));
  if ((tid & 63) == 0) red[tid >> 6] = m;
  __syncthreads();
  m = fmaxf(fmaxf(red[0], red[1]), fmaxf(red[2], red[3]));
  float s = 0.f;
  #pragma unroll
  for (int k = 0; k < 4; ++k) { s += expf(v0[k] - m); s += expf(v1[k] - m); }
  #pragma unroll
  for (int o = 32; o; o >>= 1) s += __shfl_xor(s, o);
  if ((tid & 63) == 0) red[4 + (tid >> 6)] = s;
  __syncthreads();
  s = red[4] + red[5] + red[6] + red[7];
  if (tid == 0) { mx[h * N_TOK + row] = m; is_[h * N_TOK + row] = 1.0f / s; }
}

// P^T write from f32 sim. (fallback path only)
__global__ __launch_bounds__(256)
void pt_write(const float* __restrict__ S, long long sS,
              const float* __restrict__ mx, const float* __restrict__ is_,
              unsigned short* __restrict__ PT, long long sP)
{
  const int tid = threadIdx.x;
  const size_t row = blockIdx.x;
  const size_t h = blockIdx.y;
  const f32x4* Sr = (const f32x4*)(S + (size_t)h * sS + row * N_TOK);
  const f32x4* M4 = (const f32x4*)(mx + h * N_TOK);
  const f32x4* I4 = (const f32x4*)(is_ + h * N_TOK);
  s16x4* Pr = (s16x4*)(PT + (size_t)h * sP + row * N_TOK);
  #pragma unroll
  for (int i = 0; i < 2; ++i) {
    const int idx = tid + i * 256;
    f32x4 sv = Sr[idx], mv = M4[idx], iv = I4[idx];
    s16x4 o;
    #pragma unroll
    for (int k = 0; k < 4; ++k) o[k] = (short)f2bf_u(expf(sv[k] - mv[k]) * iv[k]);
    Pr[idx] = o;
  }
}

// 4x (1024x1024) f32 -> bf16 transpose
__global__ __launch_bounds__(256)
void transpose_cast4(const float* __restrict__ w0, const float* __restrict__ w1,
                     const float* __restrict__ w2, const float* __restrict__ w3,
                     unsigned short* __restrict__ o0, unsigned short* __restrict__ o1,
                     unsigned short* __restrict__ o2, unsigned short* __restrict__ o3)
{
  __shared__ float tile[64][65];
  const float* in; unsigned short* out;
  if      (blockIdx.z == 0) { in = w0; out = o0; }
  else if (blockIdx.z == 1) { in = w1; out = o1; }
  else if (blockIdx.z == 2) { in = w2; out = o2; }
  else                      { in = w3; out = o3; }
  const int n = EMB;
  const int bx = blockIdx.x * 64, by = blockIdx.y * 64;
  const int tid = threadIdx.x;
  const int r = tid >> 2;
  const int q = tid & 3;
  #pragma unroll
  for (int i = 0; i < 4; ++i) {
    const int c = q * 16 + i * 4;
    f32x4 v = *(const f32x4*)(in + (size_t)(by + r) * n + bx + c);
    tile[r][c + 0] = v[0]; tile[r][c + 1] = v[1];
    tile[r][c + 2] = v[2]; tile[r][c + 3] = v[3];
  }
  __syncthreads();
  #pragma unroll
  for (int i = 0; i < 4; ++i) {
    const int c0 = q * 16 + i * 4;
    s16x4 o;
    o[0] = (short)f2bf_u(tile[c0 + 0][r]); o[1] = (short)f2bf_u(tile[c0 + 1][r]);
    o[2] = (short)f2bf_u(tile[c0 + 2][r]); o[3] = (short)f2bf_u(tile[c0 + 3][r]);
    *(s16x4*)(out + (size_t)(bx + r) * n + by + c0) = o;
  }
}

__global__ __launch_bounds__(256)
void cast_f32_bf16(const float* __restrict__ in, unsigned short* __restrict__ out)
{
  const size_t i = (size_t)blockIdx.x * 256 + threadIdx.x;
  f32x4 v = ((const f32x4*)in)[i];
  s16x4 o;
  o[0] = (short)f2bf_u(v[0]); o[1] = (short)f2bf_u(v[1]);
  o[2] = (short)f2bf_u(v[2]); o[3] = (short)f2bf_u(v[3]);
  ((s16x4*)out)[i] = o;
}

extern "C" void kernel_launch(void* const* d_in, const int* in_sizes, int n_in,
                              void* d_out, int out_size, void* d_ws, size_t ws_size,
                              hipStream_t stream)
{
  (void)in_sizes; (void)n_in; (void)out_size;
  const float* hs = (const float*)d_in[0];
  const float* Wq = (const float*)d_in[1];
  const float* bq = (const float*)d_in[2];
  const float* Wk = (const float*)d_in[3];
  const float* bk = (const float*)d_in[4];
  const float* Wv = (const float*)d_in[5];
  const float* bv = (const float*)d_in[6];
  const float* Wo = (const float*)d_in[7];
  const float* bo = (const float*)d_in[8];

  float* outO = (float*)d_out;                       // [2048][1024]
  float* outP = outO + (size_t)N_TOK * EMB;          // [16][2048][2048]

  const long long NN = (long long)N_TOK * N_TOK;
  const long long sH = (long long)N_TOK * HD;

  const bool batched = ws_size >= ((size_t)440 << 20);
  const int PH = batched ? N_HEADS : 1;

  char* ws = (char*)d_ws;
  auto alloc = [&](size_t b) { char* p = ws; ws += (b + 255) & ~(size_t)255; return p; };
  unsigned short* Xbf = (unsigned short*)alloc((size_t)N_TOK * EMB * 2);
  unsigned short* WqT = (unsigned short*)alloc((size_t)EMB * EMB * 2);
  unsigned short* WkT = (unsigned short*)alloc((size_t)EMB * EMB * 2);
  unsigned short* WvT = (unsigned short*)alloc((size_t)EMB * EMB * 2);
  unsigned short* WoT = (unsigned short*)alloc((size_t)EMB * EMB * 2);
  unsigned short* Qb  = (unsigned short*)alloc((size_t)N_HEADS * N_TOK * HD * 2);
  unsigned short* Kb  = (unsigned short*)alloc((size_t)N_HEADS * N_TOK * HD * 2);
  unsigned short* Vt  = (unsigned short*)alloc((size_t)N_HEADS * N_TOK * HD * 2);
  unsigned short* attn= (unsigned short*)alloc((size_t)N_TOK * EMB * 2);
  float* mxq = (float*)alloc((size_t)N_HEADS * N_TOK * 4);
  float* isq = (float*)alloc((size_t)N_HEADS * N_TOK * 4);
  float* mxk = (float*)alloc((size_t)N_HEADS * N_TOK * 4);
  float* isk = (float*)alloc((size_t)N_HEADS * N_TOK * 4);
  unsigned short* p0b = (unsigned short*)alloc((size_t)PH * NN * 2);
  unsigned short* PT  = (unsigned short*)alloc((size_t)PH * NN * 2);
  unsigned short* p1b = (unsigned short*)alloc((size_t)PH * NN * 2);

  cast_f32_bf16<<<dim3(N_TOK * EMB / 1024), 256, 0, stream>>>(hs, Xbf);
  transpose_cast4<<<dim3(16, 16, 4), 256, 0, stream>>>(Wq, Wk, Wv, Wo, WqT, WkT, WvT, WoT);

  // merged Q/K/V projection (384 blocks)
  proj_qkv<<<dim3(EMB / 128, N_TOK / 128, 3), 256, 0, stream>>>(
      Xbf, WqT, WkT, WvT, bq, bk, bv, Qb, Kb, Vt);

  if (batched) {
    // merged stats (512 blocks): QK^T -> mxq/isq, KK^T -> mxk/isk
    gemm_stats<<<dim3(16, 32), 256, 0, stream>>>(Qb, Kb, sH, mxq, isq, mxk, isk);
    // merged emit (512 blocks): p0 (row-norm) and PT (col-norm via symmetry)
    emit_merged<<<dim3(16, 16, 32), 256, 0, stream>>>(
        Qb, Kb, sH, mxq, isq, mxk, isk, p0b, PT, NN);
    // diffusion (r6 schedule, coalesced epilogues)
    gemm256_diff<EPI_DIFF_BF16><<<dim3(8, 8, N_HEADS), 512, 0, stream>>>(
        p0b, N_TOK, NN, PT, N_TOK, NN, N_TOK, p0b, N_TOK, NN, p1b, N_TOK, NN);
    gemm256_diff<EPI_DIFF_F32><<<dim3(8, 8, N_HEADS), 512, 0, stream>>>(
        p1b, N_TOK, NN, PT, N_TOK, NN, N_TOK, p0b, N_TOK, NN, outP, N_TOK, NN);
    // attn = p2 @ V (f32 A path)
    gemm_tn<128, 64, true, EPI_BF16><<<dim3(1, N_TOK / 128, N_HEADS), 256, 0, stream>>>(
        outP, N_TOK, NN, Vt, N_TOK, (long long)HD * N_TOK,
        N_TOK, 0.f, nullptr, nullptr, 0, 0, attn, EMB, HD);
  } else {
    for (int h = 0; h < N_HEADS; ++h) {
      float* slot = outP + (size_t)h * NN;
      const unsigned short* Qh = Qb + (size_t)h * N_TOK * HD;
      const unsigned short* Kh = Kb + (size_t)h * N_TOK * HD;
      gemm_tn<128, 128, false, EPI_F32SCALE><<<dim3(16, 16, 1), 256, 0, stream>>>(
          Qh, HD, 0, Kh, HD, 0, HD, 0.125f, nullptr, nullptr, 0, 0, slot, N_TOK, 0);
      row_softmax<<<dim3(N_TOK, 1), 256, 0, stream>>>(slot, 0, p0b, 0);
      gemm_tn<128, 128, false, EPI_F32SCALE><<<dim3(16, 16, 1), 256, 0, stream>>>(
          Kh, HD, 0, Kh, HD, 0, HD, 0.125f, nullptr, nullptr, 0, 0, slot, N_TOK, 0);
      row_reduce<<<dim3(N_TOK, 1), 256, 0, stream>>>(slot, 0, mxq, isq);
      pt_write<<<dim3(N_TOK, 1), 256, 0, stream>>>(slot, 0, mxq, isq, PT, 0);
      gemm_tn<128, 128, false, EPI_DIFF_BF16><<<dim3(16, 16, 1), 256, 0, stream>>>(
          p0b, N_TOK, 0, PT, N_TOK, 0, N_TOK, 0.f, nullptr, p0b, N_TOK, 0, p1b, N_TOK, 0);
      gemm_tn<128, 128, false, EPI_DIFF_F32><<<dim3(16, 16, 1), 256, 0, stream>>>(
          p1b, N_TOK, 0, PT, N_TOK, 0, N_TOK, 0.f, nullptr, p0b, N_TOK, 0, slot, N_TOK, 0);
    }
    gemm_tn<128, 64, true, EPI_BF16><<<dim3(1, N_TOK / 128, N_HEADS), 256, 0, stream>>>(
        outP, N_TOK, NN, Vt, N_TOK, (long long)HD * N_TOK,
        N_TOK, 0.f, nullptr, nullptr, 0, 0, attn, EMB, HD);
  }

  gemm_tn<128, 128, false, EPI_F32BIAS><<<dim3(EMB / 128, N_TOK / 128, 1), 256, 0, stream>>>(
      attn, EMB, 0, WoT, EMB, 0, EMB, 0.f, bo, nullptr, 0, 0, outO, EMB, 0);
}

// Round 14
// 922.224 us; speedup vs baseline: 1.0609x; 1.0609x over previous
//
#include <hip/hip_runtime.h>

// ---------------------------------------------------------------------------
// MultiHeadQGFDLayer: out = (attn @ Wo + bo), p = diffused attention
// Round 14: exact revert to r12 (923us proven). r13 post-mortem: epilogue
// write-coalescing theory FALSIFIED (WRITE_SIZE 275->263MB only, diffusion
// dur unchanged; emit repack cost +55us). HW already merges lane-scattered
// 2B fragment stores. Final config: r6-schedule diffusion (312us, 881 TF,
// 0 bank conflicts), merged proj/stats/emit, flash-style stats+emit softmax.
// ---------------------------------------------------------------------------

typedef __attribute__((ext_vector_type(8))) short bf16x8;
typedef __attribute__((ext_vector_type(4))) short s16x4;
typedef __attribute__((ext_vector_type(4))) float f32x4;

constexpr int N_TOK   = 2048;
constexpr int N_HEADS = 16;
constexpr int HD      = 64;
constexpr int EMB     = 1024;

#define DEVINL __device__ __forceinline__

DEVINL unsigned short f2bf_u(float f) {           // f32 -> bf16 (RTNE)
  unsigned x = __float_as_uint(f);
  return (unsigned short)((x + 0x7fffu + ((x >> 16) & 1u)) >> 16);
}
DEVINL float bf2f_u(unsigned short h) { return __uint_as_float(((unsigned)h) << 16); }

DEVINL void async16(const void* src, void* dst) { // global -> LDS, 16B/lane
  __builtin_amdgcn_global_load_lds(
      (const __attribute__((address_space(1))) void*)src,
      (__attribute__((address_space(3))) void*)dst, 16, 0, 0);
}

enum : int { EPI_F32SCALE = 0, EPI_F32BIAS, EPI_BF16, EPI_QKSPLIT, EPI_VSPLIT,
             EPI_DIFF_BF16, EPI_DIFF_F32 };

// ===========================================================================
// Merged QK^T / KK^T row stats: grid (16 rowblocks, 32).
// y<16: A=Q[head] -> mxq/isq ; y>=16: A=K[head] -> mxk/isk. B=K[head] always.
// ===========================================================================
__global__ __launch_bounds__(256)
void gemm_stats(const unsigned short* __restrict__ Qm,
                const unsigned short* __restrict__ Km, long long sH_,
                float* __restrict__ mxq, float* __restrict__ isq,
                float* __restrict__ mxk, float* __restrict__ isk)
{
  __shared__ __align__(16) char smem[3 * 16384];      // A 16KB + B dbuf 2x16KB
  __shared__ float lred[2][2][128];                   // [max|sum][wc][row]
  const int tid = threadIdx.x, lane = tid & 63, wv = tid >> 6;
  const int wr = wv >> 1, wc = wv & 1, l15 = lane & 15, g = lane >> 4;
  const int y = blockIdx.y;
  const size_t head = (size_t)(y & 15);
  const int sel = y >> 4;
  const unsigned short* Az = (sel ? Km : Qm) + head * (size_t)sH_
                             + (size_t)blockIdx.x * 128 * HD;
  const unsigned short* Bz = Km + head * (size_t)sH_;
  float* mxo = sel ? mxk : mxq;
  float* iso = sel ? isk : isq;
  const float alpha = 0.125f;
  const int cbs = (tid & 7) * 16;
  const int rr = tid >> 3;                            // 0..31

  #pragma unroll
  for (int i = 0; i < 4; ++i) {                       // A rows of this block
    const int r = i * 32 + rr;
    async16((const char*)Az + (size_t)r * 128 + (cbs ^ ((r & 7) << 4)),
            smem + i * 4096 + wv * 1024);
  }
  #pragma unroll
  for (int i = 0; i < 4; ++i) {                       // B tile 0 -> buf0
    const int r = i * 32 + rr;
    async16((const char*)Bz + (size_t)r * 128 + (cbs ^ ((r & 7) << 4)),
            smem + 16384 + i * 4096 + wv * 1024);
  }
  __syncthreads();

  float rm[4][4], rs[4][4];
  #pragma unroll
  for (int m = 0; m < 4; ++m)
    #pragma unroll
    for (int j = 0; j < 4; ++j) { rm[m][j] = -3.0e38f; rs[m][j] = 0.f; }

  for (int ct = 0; ct < 16; ++ct) {
    const int cur = ct & 1;
    if (ct + 1 < 16) {
      const int nb = cur ^ 1;
      #pragma unroll
      for (int i = 0; i < 4; ++i) {
        const int r = i * 32 + rr;
        const size_t br = (size_t)(ct + 1) * 128 + r;
        async16((const char*)Bz + br * 128 + (cbs ^ ((r & 7) << 4)),
                smem + 16384 + nb * 16384 + i * 4096 + wv * 1024);
      }
    }
    f32x4 acc[4][4];
    #pragma unroll
    for (int m = 0; m < 4; ++m)
      #pragma unroll
      for (int n = 0; n < 4; ++n) acc[m][n] = f32x4{0.f, 0.f, 0.f, 0.f};
    #pragma unroll
    for (int kk = 0; kk < 2; ++kk) {
      bf16x8 a[4], b[4];
      #pragma unroll
      for (int m = 0; m < 4; ++m) {
        const int row = wr * 64 + m * 16 + l15;
        const int c = (kk * 64 + g * 16) ^ ((row & 7) << 4);
        a[m] = *(const bf16x8*)(smem + row * 128 + c);
      }
      #pragma unroll
      for (int n = 0; n < 4; ++n) {
        const int row = wc * 64 + n * 16 + l15;
        const int c = (kk * 64 + g * 16) ^ ((row & 7) << 4);
        b[n] = *(const bf16x8*)(smem + 16384 + cur * 16384 + row * 128 + c);
      }
      #pragma unroll
      for (int m = 0; m < 4; ++m)
        #pragma unroll
        for (int n = 0; n < 4; ++n)
          acc[m][n] = __builtin_amdgcn_mfma_f32_16x16x32_bf16(a[m], b[n], acc[m][n], 0, 0, 0);
    }
    #pragma unroll
    for (int m = 0; m < 4; ++m)
    #pragma unroll
    for (int j = 0; j < 4; ++j) {
      const float v0 = acc[m][0][j] * alpha, v1 = acc[m][1][j] * alpha;
      const float v2 = acc[m][2][j] * alpha, v3 = acc[m][3][j] * alpha;
      const float pm = fmaxf(fmaxf(v0, v1), fmaxf(v2, v3));
      const float nm = fmaxf(rm[m][j], pm);
      rs[m][j] = rs[m][j] * expf(rm[m][j] - nm)
               + expf(v0 - nm) + expf(v1 - nm) + expf(v2 - nm) + expf(v3 - nm);
      rm[m][j] = nm;
    }
    __syncthreads();
  }

  #pragma unroll
  for (int off = 1; off < 16; off <<= 1) {
    #pragma unroll
    for (int m = 0; m < 4; ++m)
    #pragma unroll
    for (int j = 0; j < 4; ++j) {
      const float om = __shfl_xor(rm[m][j], off);
      const float os = __shfl_xor(rs[m][j], off);
      const float nm = fmaxf(rm[m][j], om);
      rs[m][j] = rs[m][j] * expf(rm[m][j] - nm) + os * expf(om - nm);
      rm[m][j] = nm;
    }
  }
  if (l15 == 0) {
    #pragma unroll
    for (int m = 0; m < 4; ++m)
    #pragma unroll
    for (int j = 0; j < 4; ++j) {
      const int r = wr * 64 + m * 16 + g * 4 + j;
      lred[0][wc][r] = rm[m][j];
      lred[1][wc][r] = rs[m][j];
    }
  }
  __syncthreads();
  if (tid < 128) {
    const float m0 = lred[0][0][tid], m1 = lred[0][1][tid];
    const float M = fmaxf(m0, m1);
    const float S = lred[1][0][tid] * expf(m0 - M) + lred[1][1][tid] * expf(m1 - M);
    mxo[head * N_TOK + (size_t)blockIdx.x * 128 + tid] = M;
    iso[head * N_TOK + (size_t)blockIdx.x * 128 + tid] = 1.0f / S;
  }
}

// ===========================================================================
// Merged emit: grid (16,16,32). z<16: p0 = rownorm exp(QK^T/8) -> p0b[head];
// z>=16: PT = colnorm exp(KK^T/8) -> PT[head] (sim symmetry). K=64.
// ===========================================================================
__global__ __launch_bounds__(256)
void emit_merged(const unsigned short* __restrict__ Qm,
                 const unsigned short* __restrict__ Km, long long sH_,
                 const float* __restrict__ mxq, const float* __restrict__ isq,
                 const float* __restrict__ mxk, const float* __restrict__ isk,
                 unsigned short* __restrict__ p0b, unsigned short* __restrict__ PTb,
                 long long sNN)
{
  constexpr int BKk = 64;
  __shared__ __align__(16) char smem[128 * BKk * 2 + 128 * BKk * 2];
  const int tid  = threadIdx.x;
  const int lane = tid & 63, wv = tid >> 6;
  const int wr = wv >> 1, wc = wv & 1;
  const int l15 = lane & 15, g = lane >> 4;
  const int zz = blockIdx.z;
  const size_t head = (size_t)(zz & 15);
  const int col = zz >> 4;
  const size_t brow = (size_t)blockIdx.y * 128;
  const size_t bcol = (size_t)blockIdx.x * 128;

  const unsigned short* Ab = (col ? Km : Qm) + head * (size_t)sH_;
  const unsigned short* Bb = Km + head * (size_t)sH_;
  unsigned short* Cu = (col ? PTb : p0b) + head * (size_t)sNN;
  const float* mxp = col ? mxk : mxq;
  const float* isp = col ? isk : isq;

  f32x4 acc[4][4];
  #pragma unroll
  for (int m = 0; m < 4; ++m)
    #pragma unroll
    for (int n = 0; n < 4; ++n) acc[m][n] = f32x4{0.f, 0.f, 0.f, 0.f};

  { // single K-tile (K = 64): 128 rows x 8 chunks = 1024 chunks = 4 iters
    #pragma unroll
    for (int i = 0; i < 4; ++i) {
      const int c   = i * 256 + wv * 64 + lane;
      const int row = c / 8;
      const int eo  = (c % 8) * 8;
      async16(Ab + (brow + row) * (size_t)HD + eo,
              smem + (size_t)(i * 256 + wv * 64) * 16);
    }
    #pragma unroll
    for (int i = 0; i < 4; ++i) {
      const int c   = i * 256 + wv * 64 + lane;
      const int row = c / 8;
      const int eo  = (c % 8) * 8;
      async16(Bb + (bcol + row) * (size_t)HD + eo,
              smem + 16384 + (size_t)(i * 256 + wv * 64) * 16);
    }
    __syncthreads();
    #pragma unroll
    for (int kk = 0; kk < 2; ++kk) {
      bf16x8 a[4], b[4];
      #pragma unroll
      for (int m = 0; m < 4; ++m) {
        const int r = wr * 64 + m * 16 + l15;
        a[m] = *(const bf16x8*)(smem + ((size_t)r * BKk + kk * 32 + g * 8) * 2);
      }
      #pragma unroll
      for (int n = 0; n < 4; ++n) {
        const int cc = wc * 64 + n * 16 + l15;
        b[n] = *(const bf16x8*)(smem + 16384 + ((size_t)cc * BKk + kk * 32 + g * 8) * 2);
      }
      #pragma unroll
      for (int m = 0; m < 4; ++m)
        #pragma unroll
        for (int n = 0; n < 4; ++n)
          acc[m][n] = __builtin_amdgcn_mfma_f32_16x16x32_bf16(a[m], b[n], acc[m][n], 0, 0, 0);
    }
    __syncthreads();
  }

  #pragma unroll
  for (int m = 0; m < 4; ++m)
  #pragma unroll
  for (int n = 0; n < 4; ++n)
  #pragma unroll
  for (int j = 0; j < 4; ++j) {
    const size_t R  = brow + (size_t)(wr * 64 + m * 16 + g * 4 + j);
    const size_t Cc = bcol + (size_t)(wc * 64 + n * 16 + l15);
    const float v = acc[m][n][j] * 0.125f;
    const size_t si = head * N_TOK + (col ? Cc : R);
    Cu[R * N_TOK + Cc] = f2bf_u(expf(v - mxp[si]) * isp[si]);
  }
}

// ===========================================================================
// Merged QKV projection: grid (8,16,3). z selects W/bias/epilogue.
// z<2: head-split [h][n][d] (Q or K); z=2: transposed split [h][d][n] (V).
// ===========================================================================
__global__ __launch_bounds__(256)
void proj_qkv(const unsigned short* __restrict__ Xbf,
              const unsigned short* __restrict__ W0, const unsigned short* __restrict__ W1,
              const unsigned short* __restrict__ W2,
              const float* __restrict__ b0, const float* __restrict__ b1,
              const float* __restrict__ b2,
              unsigned short* __restrict__ Qb, unsigned short* __restrict__ Kb,
              unsigned short* __restrict__ Vt)
{
  constexpr int BKk = 64;
  __shared__ __align__(16) char smem[2 * 128 * BKk * 2];
  const int tid  = threadIdx.x;
  const int lane = tid & 63, wv = tid >> 6;
  const int wr = wv >> 1, wc = wv & 1;
  const int l15 = lane & 15, g = lane >> 4;
  const int z = blockIdx.z;
  const size_t brow = (size_t)blockIdx.y * 128;
  const size_t bcol = (size_t)blockIdx.x * 128;

  const unsigned short* Bb = z == 0 ? W0 : (z == 1 ? W1 : W2);
  const float* bias = z == 0 ? b0 : (z == 1 ? b1 : b2);

  f32x4 acc[4][4];
  #pragma unroll
  for (int m = 0; m < 4; ++m)
    #pragma unroll
    for (int n = 0; n < 4; ++n) acc[m][n] = f32x4{0.f, 0.f, 0.f, 0.f};

  for (int k0 = 0; k0 < EMB; k0 += BKk) {
    #pragma unroll
    for (int i = 0; i < 4; ++i) {   // 128 rows x 8 chunks = 4 iters
      const int c   = i * 256 + wv * 64 + lane;
      const int row = c / 8;
      const int eo  = (c % 8) * 8;
      async16(Xbf + (brow + row) * (size_t)EMB + (size_t)(k0 + eo),
              smem + (size_t)(i * 256 + wv * 64) * 16);
    }
    #pragma unroll
    for (int i = 0; i < 4; ++i) {
      const int c   = i * 256 + wv * 64 + lane;
      const int row = c / 8;
      const int eo  = (c % 8) * 8;
      async16(Bb + (bcol + row) * (size_t)EMB + (size_t)(k0 + eo),
              smem + 16384 + (size_t)(i * 256 + wv * 64) * 16);
    }
    __syncthreads();
    #pragma unroll
    for (int kk = 0; kk < 2; ++kk) {
      bf16x8 a[4], b[4];
      #pragma unroll
      for (int m = 0; m < 4; ++m) {
        const int r = wr * 64 + m * 16 + l15;
        a[m] = *(const bf16x8*)(smem + ((size_t)r * BKk + kk * 32 + g * 8) * 2);
      }
      #pragma unroll
      for (int n = 0; n < 4; ++n) {
        const int cc = wc * 64 + n * 16 + l15;
        b[n] = *(const bf16x8*)(smem + 16384 + ((size_t)cc * BKk + kk * 32 + g * 8) * 2);
      }
      #pragma unroll
      for (int m = 0; m < 4; ++m)
        #pragma unroll
        for (int n = 0; n < 4; ++n)
          acc[m][n] = __builtin_amdgcn_mfma_f32_16x16x32_bf16(a[m], b[n], acc[m][n], 0, 0, 0);
    }
    __syncthreads();
  }

  unsigned short* dstQK = z ? Kb : Qb;
  #pragma unroll
  for (int m = 0; m < 4; ++m)
  #pragma unroll
  for (int n = 0; n < 4; ++n)
  #pragma unroll
  for (int j = 0; j < 4; ++j) {
    const size_t R  = brow + (size_t)(wr * 64 + m * 16 + g * 4 + j);
    const size_t Cc = bcol + (size_t)(wc * 64 + n * 16 + l15);
    const float t = acc[m][n][j] + bias[Cc];
    if (z == 2)
      Vt[(Cc >> 6) * ((size_t)HD * N_TOK) + (Cc & 63) * (size_t)N_TOK + R] = f2bf_u(t);
    else
      dstQK[(Cc >> 6) * ((size_t)N_TOK * HD) + R * HD + (Cc & 63)] = f2bf_u(t);
  }
}

// ===========================================================================
// 256x256 pipelined diffusion GEMM (r6 schedule, verbatim — best measured).
// ===========================================================================
template<int EPI>
__global__ __launch_bounds__(512, 2)
void gemm256_diff(const unsigned short* __restrict__ Am, int lda, long long sAz,
                  const unsigned short* __restrict__ Bm, int ldb, long long sBz,
                  int K,
                  const unsigned short* __restrict__ P0, int ldp0, long long sPz,
                  void* __restrict__ Cv, int ldc, long long sCz)
{
  __shared__ __align__(16) char smem[2 * 65536];  // 128 KiB
  const int tid  = threadIdx.x;
  const int lane = tid & 63, wv = tid >> 6;
  const int wr = wv >> 2, wc = wv & 3;            // 2 x 4 wave grid
  const int l15 = lane & 15, g = lane >> 4;
  const int z = blockIdx.z;
  const size_t brow = (size_t)blockIdx.y * 256;
  const size_t bcol = (size_t)blockIdx.x * 256;

  const unsigned short* Ab = Am + (size_t)z * (size_t)sAz;
  const unsigned short* Bb = Bm + (size_t)z * (size_t)sBz;
  const int NT = K >> 6;

  const int cbs = (tid & 7) * 16;
  const int r00 = (tid >> 3),       r01 = 64  + (tid >> 3);
  const int r10 = 128 + (tid >> 3), r11 = 192 + (tid >> 3);
  const char* gA00 = (const char*)Ab + ((brow + r00) * (size_t)lda) * 2 + (cbs ^ ((r00 & 7) << 4));
  const char* gA01 = (const char*)Ab + ((brow + r01) * (size_t)lda) * 2 + (cbs ^ ((r01 & 7) << 4));
  const char* gA10 = (const char*)Ab + ((brow + r10) * (size_t)lda) * 2 + (cbs ^ ((r10 & 7) << 4));
  const char* gA11 = (const char*)Ab + ((brow + r11) * (size_t)lda) * 2 + (cbs ^ ((r11 & 7) << 4));
  const char* gB00 = (const char*)Bb + ((bcol + r00) * (size_t)ldb) * 2 + (cbs ^ ((r00 & 7) << 4));
  const char* gB01 = (const char*)Bb + ((bcol + r01) * (size_t)ldb) * 2 + (cbs ^ ((r01 & 7) << 4));
  const char* gB10 = (const char*)Bb + ((bcol + r10) * (size_t)ldb) * 2 + (cbs ^ ((r10 & 7) << 4));
  const char* gB11 = (const char*)Bb + ((bcol + r11) * (size_t)ldb) * 2 + (cbs ^ ((r11 & 7) << 4));

  f32x4 acc[8][4];
  #pragma unroll
  for (int m = 0; m < 8; ++m)
    #pragma unroll
    for (int n = 0; n < 4; ++n) acc[m][n] = f32x4{0.f, 0.f, 0.f, 0.f};

  auto ldA = [&](int cur, int mf, int kk) -> bf16x8 {
    const int row = wr * 128 + mf * 16 + l15;
    const int c = (kk * 64 + g * 16) ^ ((row & 7) << 4);
    return *(const bf16x8*)(smem + cur * 65536 + row * 128 + c);
  };
  auto ldB = [&](int cur, int nf, int kk) -> bf16x8 {
    const int row = wc * 64 + nf * 16 + l15;
    const int c = (kk * 64 + g * 16) ^ ((row & 7) << 4);
    return *(const bf16x8*)(smem + cur * 65536 + 32768 + row * 128 + c);
  };

  {
    char* d0 = smem;
    async16(gA00, d0 +             wv * 1024);
    async16(gA01, d0 +  8192 +     wv * 1024);
    async16(gA10, d0 + 16384 +     wv * 1024);
    async16(gA11, d0 + 24576 +     wv * 1024);
    async16(gB00, d0 + 32768 +     wv * 1024);
    async16(gB01, d0 + 40960 +     wv * 1024);
    async16(gB10, d0 + 49152 +     wv * 1024);
    async16(gB11, d0 + 57344 +     wv * 1024);
    if (NT > 1) {
      char* d1 = smem + 65536 + 32768;
      async16(gB00 + 128, d1 +             wv * 1024);
      async16(gB01 + 128, d1 +  8192 +     wv * 1024);
      async16(gB10 + 128, d1 + 16384 +     wv * 1024);
      async16(gB11 + 128, d1 + 24576 +     wv * 1024);
      asm volatile("s_waitcnt vmcnt(4)" ::: "memory");
    } else {
      asm volatile("s_waitcnt vmcnt(0)" ::: "memory");
    }
    __builtin_amdgcn_sched_barrier(0);
    __builtin_amdgcn_s_barrier();
  }

#define READA(P, Q)                                                       \
    bf16x8 P##00 = ldA(cur, 2*(Q),   0), P##01 = ldA(cur, 2*(Q),   1),    \
           P##10 = ldA(cur, 2*(Q)+1, 0), P##11 = ldA(cur, 2*(Q)+1, 1);

#define MFMA16(P, Q)                                                                        \
    __builtin_amdgcn_s_setprio(1);                                                          \
    acc[2*(Q)+0][0] = __builtin_amdgcn_mfma_f32_16x16x32_bf16(P##00, b00, acc[2*(Q)+0][0], 0, 0, 0); \
    acc[2*(Q)+0][1] = __builtin_amdgcn_mfma_f32_16x16x32_bf16(P##00, b10, acc[2*(Q)+0][1], 0, 0, 0); \
    acc[2*(Q)+0][2] = __builtin_amdgcn_mfma_f32_16x16x32_bf16(P##00, b20, acc[2*(Q)+0][2], 0, 0, 0); \
    acc[2*(Q)+0][3] = __builtin_amdgcn_mfma_f32_16x16x32_bf16(P##00, b30, acc[2*(Q)+0][3], 0, 0, 0); \
    acc[2*(Q)+1][0] = __builtin_amdgcn_mfma_f32_16x16x32_bf16(P##10, b00, acc[2*(Q)+1][0], 0, 0, 0); \
    acc[2*(Q)+1][1] = __builtin_amdgcn_mfma_f32_16x16x32_bf16(P##10, b10, acc[2*(Q)+1][1], 0, 0, 0); \
    acc[2*(Q)+1][2] = __builtin_amdgcn_mfma_f32_16x16x32_bf16(P##10, b20, acc[2*(Q)+1][2], 0, 0, 0); \
    acc[2*(Q)+1][3] = __builtin_amdgcn_mfma_f32_16x16x32_bf16(P##10, b30, acc[2*(Q)+1][3], 0, 0, 0); \
    acc[2*(Q)+0][0] = __builtin_amdgcn_mfma_f32_16x16x32_bf16(P##01, b01, acc[2*(Q)+0][0], 0, 0, 0); \
    acc[2*(Q)+0][1] = __builtin_amdgcn_mfma_f32_16x16x32_bf16(P##01, b11, acc[2*(Q)+0][1], 0, 0, 0); \
    acc[2*(Q)+0][2] = __builtin_amdgcn_mfma_f32_16x16x32_bf16(P##01, b21, acc[2*(Q)+0][2], 0, 0, 0); \
    acc[2*(Q)+0][3] = __builtin_amdgcn_mfma_f32_16x16x32_bf16(P##01, b31, acc[2*(Q)+0][3], 0, 0, 0); \
    acc[2*(Q)+1][0] = __builtin_amdgcn_mfma_f32_16x16x32_bf16(P##11, b01, acc[2*(Q)+1][0], 0, 0, 0); \
    acc[2*(Q)+1][1] = __builtin_amdgcn_mfma_f32_16x16x32_bf16(P##11, b11, acc[2*(Q)+1][1], 0, 0, 0); \
    acc[2*(Q)+1][2] = __builtin_amdgcn_mfma_f32_16x16x32_bf16(P##11, b21, acc[2*(Q)+1][2], 0, 0, 0); \
    acc[2*(Q)+1][3] = __builtin_amdgcn_mfma_f32_16x16x32_bf16(P##11, b31, acc[2*(Q)+1][3], 0, 0, 0); \
    __builtin_amdgcn_s_setprio(0);

#define SB __builtin_amdgcn_sched_barrier(0)

  int cur = 0;
  for (int t = 0; t < NT; ++t, cur ^= 1) {
    const int o = cur ^ 1;
    const size_t ko1 = (size_t)(t + 1) * 128;
    const size_t ko2 = (size_t)(t + 2) * 128;
    bf16x8 b00 = ldB(cur, 0, 0), b01 = ldB(cur, 0, 1);
    bf16x8 b10 = ldB(cur, 1, 0), b11 = ldB(cur, 1, 1);
    bf16x8 b20 = ldB(cur, 2, 0), b21 = ldB(cur, 2, 1);
    bf16x8 b30 = ldB(cur, 3, 0), b31 = ldB(cur, 3, 1);
    READA(f0_, 0)
    READA(f1_, 1)
    if (t + 1 < NT) {
      char* d = smem + o * 65536;
      async16(gA00 + ko1, d +        wv * 1024);
      async16(gA01 + ko1, d + 8192 + wv * 1024);
    }
    asm volatile("s_waitcnt lgkmcnt(4)" ::: "memory");
    SB;
    MFMA16(f0_, 0)
    READA(f2_, 2)
    if (t + 1 < NT) {
      char* d = smem + o * 65536;
      async16(gA10 + ko1, d + 16384 + wv * 1024);
      async16(gA11 + ko1, d + 24576 + wv * 1024);
    }
    asm volatile("s_waitcnt lgkmcnt(4)" ::: "memory");
    SB;
    MFMA16(f1_, 1)
    SB;
    __builtin_amdgcn_s_barrier();   // all waves hold B(t) in regs now
    READA(f3_, 3)
    if (t + 2 < NT) {
      char* d = smem + cur * 65536 + 32768;
      async16(gB00 + ko2, d +        wv * 1024);
      async16(gB01 + ko2, d + 8192 + wv * 1024);
    }
    asm volatile("s_waitcnt lgkmcnt(4)" ::: "memory");
    SB;
    MFMA16(f2_, 2)
    if (t + 2 < NT) {
      char* d = smem + cur * 65536 + 32768 + 16384;
      async16(gB10 + ko2, d +        wv * 1024);
      async16(gB11 + ko2, d + 8192 + wv * 1024);
    }
    asm volatile("s_waitcnt lgkmcnt(0)" ::: "memory");
    SB;
    MFMA16(f3_, 3)
    if (t + 1 < NT) {
      if (t + 2 < NT) asm volatile("s_waitcnt vmcnt(4)" ::: "memory");
      else            asm volatile("s_waitcnt vmcnt(0)" ::: "memory");
      SB;
      __builtin_amdgcn_s_barrier();
    }
  }
#undef MFMA16
#undef READA
#undef SB

  float* Cf = (float*)Cv + (size_t)z * (size_t)sCz;
  unsigned short* Cu = (unsigned short*)Cv + (size_t)z * (size_t)sCz;
  const unsigned short* P0z = P0 + (size_t)z * (size_t)sPz;
  #pragma unroll
  for (int m = 0; m < 8; ++m)
  #pragma unroll
  for (int n = 0; n < 4; ++n)
  #pragma unroll
  for (int j = 0; j < 4; ++j) {
    const size_t R = brow + (size_t)(wr * 128 + m * 16 + g * 4 + j);
    const size_t C = bcol + (size_t)(wc * 64 + n * 16 + l15);
    const float v = acc[m][n][j];
    const float p0v = bf2f_u(P0z[R * (size_t)ldp0 + C]);
    const float r = 0.7f * p0v + 0.3f * v;
    if constexpr (EPI == EPI_DIFF_BF16) Cu[R * ldc + C] = f2bf_u(r);
    else                                Cf[R * ldc + C] = r;
  }
}

// ===========================================================================
// 128-tile kernel (pV, Wo, fallback path).
// ===========================================================================
template<int BM, int BN, bool AF32, int EPI>
__global__ __launch_bounds__(256)
void gemm_tn(const void* __restrict__ Av, int lda, long long sAz,
             const unsigned short* __restrict__ Bm, int ldb, long long sBz,
             int K, float alpha, const float* __restrict__ bias,
             const unsigned short* __restrict__ P0, int ldp0, long long sPz,
             void* __restrict__ Cv, int ldc, long long sCz)
{
  constexpr int BKk = 64;
  constexpr int WM = BM / 2, WN = BN / 2, MF = WM / 16, NF = WN / 16;
  constexpr int AES = AF32 ? 4 : 2;
  constexpr int ABYTES = BM * BKk * AES, BBYTES = BN * BKk * 2;
  __shared__ __align__(16) char smem[ABYTES + BBYTES];

  const int tid  = threadIdx.x;
  const int lane = tid & 63, wv = tid >> 6;
  const int wr = wv >> 1, wc = wv & 1;
  const int l15 = lane & 15, g = lane >> 4;
  const int z = blockIdx.z;
  const size_t brow = (size_t)blockIdx.y * BM;
  const size_t bcol = (size_t)blockIdx.x * BN;

  const char* Ab = (const char*)Av + (size_t)z * (size_t)sAz * AES;
  const unsigned short* Bb = Bm + (size_t)z * (size_t)sBz;

  f32x4 acc[MF][NF];
  #pragma unroll
  for (int m = 0; m < MF; ++m)
    #pragma unroll
    for (int n = 0; n < NF; ++n)
      acc[m][n] = f32x4{0.f, 0.f, 0.f, 0.f};

  constexpr int EPC_A = AF32 ? 4 : 8;
  constexpr int CPR_A = BKk / EPC_A;
  constexpr int IT_A  = (BM * CPR_A) / 256;
  constexpr int CPR_B = 8;
  constexpr int IT_B  = (BN * CPR_B) / 256;

  for (int k0 = 0; k0 < K; k0 += BKk) {
    #pragma unroll
    for (int i = 0; i < IT_A; ++i) {
      const int c   = i * 256 + wv * 64 + lane;
      const int row = c / CPR_A;
      const int eo  = (c % CPR_A) * EPC_A;
      const char* src = Ab + ((brow + row) * (size_t)lda + (size_t)(k0 + eo)) * AES;
      async16(src, smem + (size_t)(i * 256 + wv * 64) * 16);
    }
    #pragma unroll
    for (int i = 0; i < IT_B; ++i) {
      const int c   = i * 256 + wv * 64 + lane;
      const int row = c / CPR_B;
      const int eo  = (c % CPR_B) * 8;
      const unsigned short* src = Bb + (bcol + row) * (size_t)ldb + (size_t)(k0 + eo);
      async16(src, smem + ABYTES + (size_t)(i * 256 + wv * 64) * 16);
    }
    __syncthreads();
    #pragma unroll
    for (int kk = 0; kk < 2; ++kk) {
      bf16x8 a[MF], b[NF];
      #pragma unroll
      for (int m = 0; m < MF; ++m) {
        const int r = wr * WM + m * 16 + l15;
        if constexpr (!AF32) {
          a[m] = *(const bf16x8*)(smem + ((size_t)r * BKk + kk * 32 + g * 8) * 2);
        } else {
          const float* pa = (const float*)smem + (size_t)r * BKk + kk * 32 + g * 8;
          const f32x4 lo = *(const f32x4*)pa;
          const f32x4 hi = *(const f32x4*)(pa + 4);
          bf16x8 t;
          t[0] = (short)f2bf_u(lo[0]); t[1] = (short)f2bf_u(lo[1]);
          t[2] = (short)f2bf_u(lo[2]); t[3] = (short)f2bf_u(lo[3]);
          t[4] = (short)f2bf_u(hi[0]); t[5] = (short)f2bf_u(hi[1]);
          t[6] = (short)f2bf_u(hi[2]); t[7] = (short)f2bf_u(hi[3]);
          a[m] = t;
        }
      }
      #pragma unroll
      for (int n = 0; n < NF; ++n) {
        const int cc = wc * WN + n * 16 + l15;
        b[n] = *(const bf16x8*)(smem + ABYTES + ((size_t)cc * BKk + kk * 32 + g * 8) * 2);
      }
      #pragma unroll
      for (int m = 0; m < MF; ++m)
        #pragma unroll
        for (int n = 0; n < NF; ++n)
          acc[m][n] = __builtin_amdgcn_mfma_f32_16x16x32_bf16(a[m], b[n], acc[m][n], 0, 0, 0);
    }
    __syncthreads();
  }

  float* Cf = (float*)Cv + (size_t)z * (size_t)sCz;
  unsigned short* Cu = (unsigned short*)Cv + (size_t)z * (size_t)sCz;

  #pragma unroll
  for (int m = 0; m < MF; ++m)
  #pragma unroll
  for (int n = 0; n < NF; ++n)
  #pragma unroll
  for (int j = 0; j < 4; ++j) {
    const size_t R  = brow + (size_t)(wr * WM + m * 16 + g * 4 + j);
    const size_t Cc = bcol + (size_t)(wc * WN + n * 16 + l15);
    const float v = acc[m][n][j];
    if constexpr (EPI == EPI_F32SCALE) {
      Cf[R * ldc + Cc] = v * alpha;
    } else if constexpr (EPI == EPI_F32BIAS) {
      Cf[R * ldc + Cc] = v + bias[Cc];
    } else if constexpr (EPI == EPI_BF16) {
      Cu[R * ldc + Cc] = f2bf_u(v);
    } else if constexpr (EPI == EPI_DIFF_BF16) {
      const unsigned short* P0z = P0 + (size_t)z * (size_t)sPz;
      const float p0v = bf2f_u(P0z[R * (size_t)ldp0 + Cc]);
      Cu[R * ldc + Cc] = f2bf_u(0.7f * p0v + 0.3f * v);
    } else if constexpr (EPI == EPI_DIFF_F32) {
      const unsigned short* P0z = P0 + (size_t)z * (size_t)sPz;
      const float p0v = bf2f_u(P0z[R * (size_t)ldp0 + Cc]);
      Cf[R * ldc + Cc] = 0.7f * p0v + 0.3f * v;
    }
  }
  (void)alpha; (void)bias; (void)P0; (void)ldp0;
}

// Row softmax (fallback path only)
__global__ __launch_bounds__(256)
void row_softmax(const float* __restrict__ S, long long sS,
                 unsigned short* __restrict__ O, long long sO)
{
  __shared__ float red[8];
  const int tid = threadIdx.x;
  const size_t row = blockIdx.x;
  const size_t h = blockIdx.y;
  const f32x4* Sr = (const f32x4*)(S + (size_t)h * sS + row * N_TOK);
  f32x4 v0 = Sr[tid], v1 = Sr[tid + 256];
  float m = fmaxf(fmaxf(fmaxf(v0[0], v0[1]), fmaxf(v0[2], v0[3])),
                  fmaxf(fmaxf(v1[0], v1[1]), fmaxf(v1[2], v1[3])));
  #pragma unroll
  for (int o = 32; o; o >>= 1) m = fmaxf(m, __shfl_xor(m, o));
  if ((tid & 63) == 0) red[tid >> 6] = m;
  __syncthreads();
  m = fmaxf(fmaxf(red[0], red[1]), fmaxf(red[2], red[3]));
  f32x4 e0, e1;
  #pragma unroll
  for (int k = 0; k < 4; ++k) { e0[k] = expf(v0[k] - m); e1[k] = expf(v1[k] - m); }
  float s = e0[0]+e0[1]+e0[2]+e0[3]+e1[0]+e1[1]+e1[2]+e1[3];
  #pragma unroll
  for (int o = 32; o; o >>= 1) s += __shfl_xor(s, o);
  if ((tid & 63) == 0) red[4 + (tid >> 6)] = s;
  __syncthreads();
  s = red[4] + red[5] + red[6] + red[7];
  const float inv = 1.0f / s;
  s16x4 o0, o1;
  #pragma unroll
  for (int k = 0; k < 4; ++k) {
    o0[k] = (short)f2bf_u(e0[k] * inv);
    o1[k] = (short)f2bf_u(e1[k] * inv);
  }
  s16x4* Or = (s16x4*)(O + (size_t)h * sO + row * N_TOK);
  Or[tid] = o0; Or[tid + 256] = o1;
}

// Row stats (fallback path only)
__global__ __launch_bounds__(256)
void row_reduce(const float* __restrict__ S, long long sS,
                float* __restrict__ mx, float* __restrict__ is_)
{
  __shared__ float red[8];
  const int tid = threadIdx.x;
  const size_t row = blockIdx.x;
  const size_t h = blockIdx.y;
  const f32x4* Sr = (const f32x4*)(S + (size_t)h * sS + row * N_TOK);
  f32x4 v0 = Sr[tid], v1 = Sr[tid + 256];
  float m = fmaxf(fmaxf(fmaxf(v0[0], v0[1]), fmaxf(v0[2], v0[3])),
                  fmaxf(fmaxf(v1[0], v1[1]), fmaxf(v1[2], v1[3])));
  #pragma unroll
  for (int o = 32; o; o >>= 1) m = fmaxf(m, __shfl_xor(m, o));
  if ((tid & 63) == 0) red[tid >> 6] = m;
  __syncthreads();
  m = fmaxf(fmaxf(red[0], red[1]), fmaxf(red[2], red[3]));
  float s = 0.f;
  #pragma unroll
  for (int k = 0; k < 4; ++k) { s += expf(v0[k] - m); s += expf(v1[k] - m); }
  #pragma unroll
  for (int o = 32; o; o >>= 1) s += __shfl_xor(s, o);
  if ((tid & 63) == 0) red[4 + (tid >> 6)] = s;
  __syncthreads();
  s = red[4] + red[5] + red[6] + red[7];
  if (tid == 0) { mx[h * N_TOK + row] = m; is_[h * N_TOK + row] = 1.0f / s; }
}

// P^T write from f32 sim. (fallback path only)
__global__ __launch_bounds__(256)
void pt_write(const float* __restrict__ S, long long sS,
              const float* __restrict__ mx, const float* __restrict__ is_,
              unsigned short* __restrict__ PT, long long sP)
{
  const int tid = threadIdx.x;
  const size_t row = blockIdx.x;
  const size_t h = blockIdx.y;
  const f32x4* Sr = (const f32x4*)(S + (size_t)h * sS + row * N_TOK);
  const f32x4* M4 = (const f32x4*)(mx + h * N_TOK);
  const f32x4* I4 = (const f32x4*)(is_ + h * N_TOK);
  s16x4* Pr = (s16x4*)(PT + (size_t)h * sP + row * N_TOK);
  #pragma unroll
  for (int i = 0; i < 2; ++i) {
    const int idx = tid + i * 256;
    f32x4 sv = Sr[idx], mv = M4[idx], iv = I4[idx];
    s16x4 o;
    #pragma unroll
    for (int k = 0; k < 4; ++k) o[k] = (short)f2bf_u(expf(sv[k] - mv[k]) * iv[k]);
    Pr[idx] = o;
  }
}

// 4x (1024x1024) f32 -> bf16 transpose
__global__ __launch_bounds__(256)
void transpose_cast4(const float* __restrict__ w0, const float* __restrict__ w1,
                     const float* __restrict__ w2, const float* __restrict__ w3,
                     unsigned short* __restrict__ o0, unsigned short* __restrict__ o1,
                     unsigned short* __restrict__ o2, unsigned short* __restrict__ o3)
{
  __shared__ float tile[64][65];
  const float* in; unsigned short* out;
  if      (blockIdx.z == 0) { in = w0; out = o0; }
  else if (blockIdx.z == 1) { in = w1; out = o1; }
  else if (blockIdx.z == 2) { in = w2; out = o2; }
  else                      { in = w3; out = o3; }
  const int n = EMB;
  const int bx = blockIdx.x * 64, by = blockIdx.y * 64;
  const int tid = threadIdx.x;
  const int r = tid >> 2;
  const int q = tid & 3;
  #pragma unroll
  for (int i = 0; i < 4; ++i) {
    const int c = q * 16 + i * 4;
    f32x4 v = *(const f32x4*)(in + (size_t)(by + r) * n + bx + c);
    tile[r][c + 0] = v[0]; tile[r][c + 1] = v[1];
    tile[r][c + 2] = v[2]; tile[r][c + 3] = v[3];
  }
  __syncthreads();
  #pragma unroll
  for (int i = 0; i < 4; ++i) {
    const int c0 = q * 16 + i * 4;
    s16x4 o;
    o[0] = (short)f2bf_u(tile[c0 + 0][r]); o[1] = (short)f2bf_u(tile[c0 + 1][r]);
    o[2] = (short)f2bf_u(tile[c0 + 2][r]); o[3] = (short)f2bf_u(tile[c0 + 3][r]);
    *(s16x4*)(out + (size_t)(bx + r) * n + by + c0) = o;
  }
}

__global__ __launch_bounds__(256)
void cast_f32_bf16(const float* __restrict__ in, unsigned short* __restrict__ out)
{
  const size_t i = (size_t)blockIdx.x * 256 + threadIdx.x;
  f32x4 v = ((const f32x4*)in)[i];
  s16x4 o;
  o[0] = (short)f2bf_u(v[0]); o[1] = (short)f2bf_u(v[1]);
  o[2] = (short)f2bf_u(v[2]); o[3] = (short)f2bf_u(v[3]);
  ((s16x4*)out)[i] = o;
}

extern "C" void kernel_launch(void* const* d_in, const int* in_sizes, int n_in,
                              void* d_out, int out_size, void* d_ws, size_t ws_size,
                              hipStream_t stream)
{
  (void)in_sizes; (void)n_in; (void)out_size;
  const float* hs = (const float*)d_in[0];
  const float* Wq = (const float*)d_in[1];
  const float* bq = (const float*)d_in[2];
  const float* Wk = (const float*)d_in[3];
  const float* bk = (const float*)d_in[4];
  const float* Wv = (const float*)d_in[5];
  const float* bv = (const float*)d_in[6];
  const float* Wo = (const float*)d_in[7];
  const float* bo = (const float*)d_in[8];

  float* outO = (float*)d_out;                       // [2048][1024]
  float* outP = outO + (size_t)N_TOK * EMB;          // [16][2048][2048]

  const long long NN = (long long)N_TOK * N_TOK;
  const long long sH = (long long)N_TOK * HD;

  const bool batched = ws_size >= ((size_t)440 << 20);
  const int PH = batched ? N_HEADS : 1;

  char* ws = (char*)d_ws;
  auto alloc = [&](size_t b) { char* p = ws; ws += (b + 255) & ~(size_t)255; return p; };
  unsigned short* Xbf = (unsigned short*)alloc((size_t)N_TOK * EMB * 2);
  unsigned short* WqT = (unsigned short*)alloc((size_t)EMB * EMB * 2);
  unsigned short* WkT = (unsigned short*)alloc((size_t)EMB * EMB * 2);
  unsigned short* WvT = (unsigned short*)alloc((size_t)EMB * EMB * 2);
  unsigned short* WoT = (unsigned short*)alloc((size_t)EMB * EMB * 2);
  unsigned short* Qb  = (unsigned short*)alloc((size_t)N_HEADS * N_TOK * HD * 2);
  unsigned short* Kb  = (unsigned short*)alloc((size_t)N_HEADS * N_TOK * HD * 2);
  unsigned short* Vt  = (unsigned short*)alloc((size_t)N_HEADS * N_TOK * HD * 2);
  unsigned short* attn= (unsigned short*)alloc((size_t)N_TOK * EMB * 2);
  float* mxq = (float*)alloc((size_t)N_HEADS * N_TOK * 4);
  float* isq = (float*)alloc((size_t)N_HEADS * N_TOK * 4);
  float* mxk = (float*)alloc((size_t)N_HEADS * N_TOK * 4);
  float* isk = (float*)alloc((size_t)N_HEADS * N_TOK * 4);
  unsigned short* p0b = (unsigned short*)alloc((size_t)PH * NN * 2);
  unsigned short* PT  = (unsigned short*)alloc((size_t)PH * NN * 2);
  unsigned short* p1b = (unsigned short*)alloc((size_t)PH * NN * 2);

  cast_f32_bf16<<<dim3(N_TOK * EMB / 1024), 256, 0, stream>>>(hs, Xbf);
  transpose_cast4<<<dim3(16, 16, 4), 256, 0, stream>>>(Wq, Wk, Wv, Wo, WqT, WkT, WvT, WoT);

  // merged Q/K/V projection (384 blocks)
  proj_qkv<<<dim3(EMB / 128, N_TOK / 128, 3), 256, 0, stream>>>(
      Xbf, WqT, WkT, WvT, bq, bk, bv, Qb, Kb, Vt);

  if (batched) {
    // merged stats (512 blocks): QK^T -> mxq/isq, KK^T -> mxk/isk
    gemm_stats<<<dim3(16, 32), 256, 0, stream>>>(Qb, Kb, sH, mxq, isq, mxk, isk);
    // merged emit (512 blocks): p0 (row-norm) and PT (col-norm via symmetry)
    emit_merged<<<dim3(16, 16, 32), 256, 0, stream>>>(
        Qb, Kb, sH, mxq, isq, mxk, isk, p0b, PT, NN);
    // diffusion (r6 schedule)
    gemm256_diff<EPI_DIFF_BF16><<<dim3(8, 8, N_HEADS), 512, 0, stream>>>(
        p0b, N_TOK, NN, PT, N_TOK, NN, N_TOK, p0b, N_TOK, NN, p1b, N_TOK, NN);
    gemm256_diff<EPI_DIFF_F32><<<dim3(8, 8, N_HEADS), 512, 0, stream>>>(
        p1b, N_TOK, NN, PT, N_TOK, NN, N_TOK, p0b, N_TOK, NN, outP, N_TOK, NN);
    // attn = p2 @ V (f32 A path)
    gemm_tn<128, 64, true, EPI_BF16><<<dim3(1, N_TOK / 128, N_HEADS), 256, 0, stream>>>(
        outP, N_TOK, NN, Vt, N_TOK, (long long)HD * N_TOK,
        N_TOK, 0.f, nullptr, nullptr, 0, 0, attn, EMB, HD);
  } else {
    for (int h = 0; h < N_HEADS; ++h) {
      float* slot = outP + (size_t)h * NN;
      const unsigned short* Qh = Qb + (size_t)h * N_TOK * HD;
      const unsigned short* Kh = Kb + (size_t)h * N_TOK * HD;
      gemm_tn<128, 128, false, EPI_F32SCALE><<<dim3(16, 16, 1), 256, 0, stream>>>(
          Qh, HD, 0, Kh, HD, 0, HD, 0.125f, nullptr, nullptr, 0, 0, slot, N_TOK, 0);
      row_softmax<<<dim3(N_TOK, 1), 256, 0, stream>>>(slot, 0, p0b, 0);
      gemm_tn<128, 128, false, EPI_F32SCALE><<<dim3(16, 16, 1), 256, 0, stream>>>(
          Kh, HD, 0, Kh, HD, 0, HD, 0.125f, nullptr, nullptr, 0, 0, slot, N_TOK, 0);
      row_reduce<<<dim3(N_TOK, 1), 256, 0, stream>>>(slot, 0, mxq, isq);
      pt_write<<<dim3(N_TOK, 1), 256, 0, stream>>>(slot, 0, mxq, isq, PT, 0);
      gemm_tn<128, 128, false, EPI_DIFF_BF16><<<dim3(16, 16, 1), 256, 0, stream>>>(
          p0b, N_TOK, 0, PT, N_TOK, 0, N_TOK, 0.f, nullptr, p0b, N_TOK, 0, p1b, N_TOK, 0);
      gemm_tn<128, 128, false, EPI_DIFF_F32><<<dim3(16, 16, 1), 256, 0, stream>>>(
          p1b, N_TOK, 0, PT, N_TOK, 0, N_TOK, 0.f, nullptr, p0b, N_TOK, 0, slot, N_TOK, 0);
    }
    gemm_tn<128, 64, true, EPI_BF16><<<dim3(1, N_TOK / 128, N_HEADS), 256, 0, stream>>>(
        outP, N_TOK, NN, Vt, N_TOK, (long long)HD * N_TOK,
        N_TOK, 0.f, nullptr, nullptr, 0, 0, attn, EMB, HD);
  }

  gemm_tn<128, 128, false, EPI_F32BIAS><<<dim3(EMB / 128, N_TOK / 128, 1), 256, 0, stream>>>(
      attn, EMB, 0, WoT, EMB, 0, EMB, 0.f, bo, nullptr, 0, 0, outO, EMB, 0);
}